// Round 1
// baseline (175.107 us; speedup 1.0000x reference)
//
#include <hip/hip_runtime.h>

// SelfAttentionBlock: B=4, C=64, N=4096, fp32 in/out.
//   q/k/v = W{q,k,v} @ x + b   (per-position 64x64 linear)
//   S = q^T k / sqrt(C); P = softmax_j(S); out = gamma * (V P^T) + x
// Strategy: bf16 MFMA flash attention. Workspace holds bf16 Q^T,K^T [B,N,C]
// and V [B,C,N] (6 MB). Scale 1/sqrt(C)*log2(e) folded into Q.

#define B_ 4
#define C_ 64
#define N_ 4096
#define LDSP 72  // LDS row stride in bf16 elements (144 B = 16B-aligned, 2-way-conflict only)

typedef short short8 __attribute__((ext_vector_type(8)));
typedef float f32x4 __attribute__((ext_vector_type(4)));

__device__ __forceinline__ short f2bf(float f) {
    __bf16 h = (__bf16)f;
    return __builtin_bit_cast(short, h);
}

__device__ __forceinline__ f32x4 mfma16(short8 a, short8 b, f32x4 c) {
    return __builtin_amdgcn_mfma_f32_16x16x32_bf16(a, b, c, 0, 0, 0);
}

// Load 8 consecutive floats of W row -> bf16x8 fragment (B- or A-operand).
__device__ __forceinline__ short8 loadWfrag(const float* __restrict__ W, int row, int kbase) {
    const float4 f0 = *(const float4*)(W + row * 64 + kbase);
    const float4 f1 = *(const float4*)(W + row * 64 + kbase + 4);
    short8 r;
    r[0] = f2bf(f0.x); r[1] = f2bf(f0.y); r[2] = f2bf(f0.z); r[3] = f2bf(f0.w);
    r[4] = f2bf(f1.x); r[5] = f2bf(f1.y); r[6] = f2bf(f1.z); r[7] = f2bf(f1.w);
    return r;
}

// QSCALE = (1/sqrt(64)) * log2(e): softmax done in base-2 with v_exp_f32.
#define QSCALE 0.18033688011111773f

__global__ __launch_bounds__(256) void proj_kernel(
    const float* __restrict__ x,
    const float* __restrict__ Wq, const float* __restrict__ bq,
    const float* __restrict__ Wk, const float* __restrict__ bk,
    const float* __restrict__ Wv, const float* __restrict__ bv,
    short* __restrict__ Qt, short* __restrict__ Kt, short* __restrict__ Vn)
{
    __shared__ __align__(16) short xT[64 * LDSP];  // x^T tile: [n][c] bf16
    const int tid = threadIdx.x;
    const int b  = blockIdx.x >> 6;
    const int n0 = (blockIdx.x & 63) << 6;

    // Stage x[b, 0:64, n0:n0+64] transposed into LDS as bf16.
    {
        const int crow = tid >> 4;  // 0..15 per pass
        const int ch   = tid & 15;  // n-chunk of 4 floats
        for (int p = 0; p < 4; ++p) {
            const int c = p * 16 + crow;
            const float4 v = *(const float4*)(x + ((size_t)(b * C_ + c)) * N_ + n0 + ch * 4);
            xT[(ch * 4 + 0) * LDSP + c] = f2bf(v.x);
            xT[(ch * 4 + 1) * LDSP + c] = f2bf(v.y);
            xT[(ch * 4 + 2) * LDSP + c] = f2bf(v.z);
            xT[(ch * 4 + 3) * LDSP + c] = f2bf(v.w);
        }
    }
    __syncthreads();

    const int wave = tid >> 6, lane = tid & 63;
    const int lo = lane & 15, hi = lane >> 4;

    // A-fragments from x^T (rows n = 16*wave + lo), shared by Q and K GEMMs.
    short8 aX[2];
    aX[0] = *(const short8*)&xT[(16 * wave + lo) * LDSP + 0 * 32 + hi * 8];
    aX[1] = *(const short8*)&xT[(16 * wave + lo) * LDSP + 1 * 32 + hi * 8];

    // Q^T and K^T: D[n][o] = x^T . W^T  (B-frag = W row, k-contiguous)
    for (int m = 0; m < 2; ++m) {
        const float* W    = m ? Wk : Wq;
        const float* bias = m ? bk : bq;
        short* dst        = m ? Kt : Qt;
        const float scale = m ? 1.0f : QSCALE;
        for (int ot = 0; ot < 4; ++ot) {
            f32x4 acc = {0.f, 0.f, 0.f, 0.f};
            for (int kh = 0; kh < 2; ++kh)
                acc = mfma16(aX[kh], loadWfrag(W, ot * 16 + lo, kh * 32 + hi * 8), acc);
            const int o = ot * 16 + lo;
            const float bsv = bias[o];
            for (int r = 0; r < 4; ++r) {
                const int n = n0 + 16 * wave + 4 * hi + r;
                dst[((size_t)(b * N_ + n)) * C_ + o] = f2bf((acc[r] + bsv) * scale);
            }
        }
    }

    // V: D[o][n] = W . x  (A-frag = W row, B-frag = x^T row)
    short8 aV[2];
    aV[0] = loadWfrag(Wv, 16 * wave + lo, 0 * 32 + hi * 8);
    aV[1] = loadWfrag(Wv, 16 * wave + lo, 1 * 32 + hi * 8);
    for (int nt = 0; nt < 4; ++nt) {
        f32x4 acc = {0.f, 0.f, 0.f, 0.f};
        for (int kh = 0; kh < 2; ++kh)
            acc = mfma16(aV[kh], *(const short8*)&xT[(nt * 16 + lo) * LDSP + kh * 32 + hi * 8], acc);
        for (int r = 0; r < 4; ++r) {
            const int o = 16 * wave + 4 * hi + r;
            const float v = acc[r] + bv[o];
            Vn[((size_t)(b * C_ + o)) * N_ + n0 + nt * 16 + lo] = f2bf(v);
        }
    }
}

__global__ __launch_bounds__(256) void attn_kernel(
    const short* __restrict__ Qt, const short* __restrict__ Kt, const short* __restrict__ Vn,
    const float* __restrict__ x, const float* __restrict__ gamma_p, float* __restrict__ out)
{
    __shared__ __align__(16) short kt[64 * LDSP];      // K^T tile [j][c]
    __shared__ __align__(16) short vt[64 * LDSP];      // V tile [c][j]
    __shared__ __align__(16) short pt[4][16 * LDSP];   // per-wave P tile [i][j]

    const int tid = threadIdx.x;
    const int b  = blockIdx.x >> 6;
    const int i0 = (blockIdx.x & 63) << 6;
    const int wave = tid >> 6, lane = tid & 63;
    const int lo = lane & 15, hi = lane >> 4;

    // Q A-fragments, loaded once: rows i = i0 + 16*wave + lo
    short8 qf[2];
    {
        const size_t qbase = ((size_t)(b * N_ + i0 + wave * 16 + lo)) * C_;
        qf[0] = *(const short8*)(Qt + qbase + 0 * 32 + hi * 8);
        qf[1] = *(const short8*)(Qt + qbase + 1 * 32 + hi * 8);
    }

    float m_r[4], l_r[4];
    f32x4 o_acc[4];
    for (int r = 0; r < 4; ++r) { m_r[r] = -1e30f; l_r[r] = 0.f; }
    for (int ct = 0; ct < 4; ++ct) o_acc[ct] = (f32x4){0.f, 0.f, 0.f, 0.f};

    const int srow = tid >> 3;  // 0..31 (staging row per pass)
    const int sch  = tid & 7;   // 16B chunk within 128B row

    for (int jt = 0; jt < 64; ++jt) {
        const int j0 = jt * 64;
        __syncthreads();  // prior iter's tile reads done before overwrite
        for (int p = 0; p < 2; ++p) {
            const int r = p * 32 + srow;
            *(uint4*)&kt[r * LDSP + sch * 8] =
                *(const uint4*)(Kt + ((size_t)(b * N_ + j0 + r)) * C_ + sch * 8);
            *(uint4*)&vt[r * LDSP + sch * 8] =
                *(const uint4*)(Vn + ((size_t)(b * C_ + r)) * N_ + j0 + sch * 8);
        }
        __syncthreads();

        // S = Q K^T (pre-scaled): wave owns rows 16w..16w+15, all 64 j
        f32x4 s[4];
        for (int j16 = 0; j16 < 4; ++j16) {
            f32x4 acc = {0.f, 0.f, 0.f, 0.f};
            for (int kh = 0; kh < 2; ++kh)
                acc = mfma16(qf[kh],
                             *(const short8*)&kt[(j16 * 16 + lo) * LDSP + kh * 32 + hi * 8],
                             acc);
            s[j16] = acc;
        }

        // Online softmax: rows live in one 16-lane group -> shuffle reduce
        float alpha[4];
        for (int r = 0; r < 4; ++r) {
            float mx = fmaxf(fmaxf(s[0][r], s[1][r]), fmaxf(s[2][r], s[3][r]));
            for (int off = 1; off < 16; off <<= 1)
                mx = fmaxf(mx, __shfl_xor(mx, off, 64));
            const float mnew = fmaxf(m_r[r], mx);
            alpha[r] = __builtin_amdgcn_exp2f(m_r[r] - mnew);
            m_r[r] = mnew;
            float sum = 0.f;
            for (int j16 = 0; j16 < 4; ++j16) {
                const float pv = __builtin_amdgcn_exp2f(s[j16][r] - mnew);
                s[j16][r] = pv;
                sum += pv;
            }
            for (int off = 1; off < 16; off <<= 1)
                sum += __shfl_xor(sum, off, 64);
            l_r[r] = l_r[r] * alpha[r] + sum;
        }

        // P: C-layout -> A-layout via per-wave LDS round-trip (bf16)
        short* pw = &pt[wave][0];
        for (int j16 = 0; j16 < 4; ++j16)
            for (int r = 0; r < 4; ++r)
                pw[(4 * hi + r) * LDSP + j16 * 16 + lo] = f2bf(s[j16][r]);
        short8 pf[2];
        pf[0] = *(const short8*)&pw[lo * LDSP + 0 * 32 + hi * 8];
        pf[1] = *(const short8*)&pw[lo * LDSP + 1 * 32 + hi * 8];

        // O = O*alpha + P V^T
        for (int ct = 0; ct < 4; ++ct) {
            f32x4 oc = o_acc[ct];
            for (int r = 0; r < 4; ++r) oc[r] *= alpha[r];
            for (int kh = 0; kh < 2; ++kh)
                oc = mfma16(pf[kh],
                            *(const short8*)&vt[(ct * 16 + lo) * LDSP + kh * 32 + hi * 8],
                            oc);
            o_acc[ct] = oc;
        }
    }

    // Epilogue: out = gamma * (O/l) + x   (l >= 1 always, so O/l finite)
    const float g = gamma_p[0];
    for (int ct = 0; ct < 4; ++ct) {
        const int c = ct * 16 + lo;
        for (int r = 0; r < 4; ++r) {
            const int n = i0 + wave * 16 + 4 * hi + r;
            const size_t idx = ((size_t)(b * C_ + c)) * N_ + n;
            out[idx] = g * (o_acc[ct][r] / l_r[r]) + x[idx];
        }
    }
}

extern "C" void kernel_launch(void* const* d_in, const int* in_sizes, int n_in,
                              void* d_out, int out_size, void* d_ws, size_t ws_size,
                              hipStream_t stream) {
    const float* x     = (const float*)d_in[0];
    const float* Wq    = (const float*)d_in[1];
    const float* bq    = (const float*)d_in[2];
    const float* Wk    = (const float*)d_in[3];
    const float* bk    = (const float*)d_in[4];
    const float* Wv    = (const float*)d_in[5];
    const float* bv    = (const float*)d_in[6];
    const float* gamma = (const float*)d_in[7];
    float* out = (float*)d_out;

    // Workspace: Q^T, K^T [B,N,C] bf16 + V [B,C,N] bf16 = 6 MB
    short* Qt = (short*)d_ws;
    short* Kt = Qt + (size_t)B_ * N_ * C_;
    short* Vn = Kt + (size_t)B_ * N_ * C_;

    proj_kernel<<<dim3(B_ * (N_ / 64)), dim3(256), 0, stream>>>(
        x, Wq, bq, Wk, bk, Wv, bv, Qt, Kt, Vn);
    attn_kernel<<<dim3(B_ * (N_ / 64)), dim3(256), 0, stream>>>(
        Qt, Kt, Vn, x, gamma, out);
}

// Round 2
// 167.765 us; speedup vs baseline: 1.0438x; 1.0438x over previous
//
#include <hip/hip_runtime.h>

// SelfAttentionBlock: B=4, C=64, N=4096, fp32 in/out.
// R2: no-max online softmax (fixed shift, shift-invariant), S^T trick kills the
// P transpose, l via ones-MFMA, split-j(4) + fp32 atomics for occupancy.

#define B_ 4
#define C_ 64
#define N_ 4096
#define LDSK 72    // stride for 64-wide bf16 rows
#define LDSV 136   // stride for 128-wide bf16 rows
#define BJ 128     // j per staging round
#define SPLIT 4
#define MSHIFT 12.0f
#define QSCALE 0.18033688011111773f  // (1/sqrt(64)) * log2(e)

typedef short short8 __attribute__((ext_vector_type(8)));
typedef short bh4 __attribute__((ext_vector_type(4)));
typedef float f32x4 __attribute__((ext_vector_type(4)));

__device__ __forceinline__ short f2bf(float f) {
    __bf16 h = (__bf16)f;
    return __builtin_bit_cast(short, h);
}

__device__ __forceinline__ f32x4 mfma16(short8 a, short8 b, f32x4 c) {
    return __builtin_amdgcn_mfma_f32_16x16x32_bf16(a, b, c, 0, 0, 0);
}

__device__ __forceinline__ short8 loadWfrag(const float* __restrict__ W, int row, int kbase) {
    const float4 f0 = *(const float4*)(W + row * 64 + kbase);
    const float4 f1 = *(const float4*)(W + row * 64 + kbase + 4);
    short8 r;
    r[0] = f2bf(f0.x); r[1] = f2bf(f0.y); r[2] = f2bf(f0.z); r[3] = f2bf(f0.w);
    r[4] = f2bf(f1.x); r[5] = f2bf(f1.y); r[6] = f2bf(f1.z); r[7] = f2bf(f1.w);
    return r;
}

__global__ void zero_ws(float* __restrict__ p, int n4) {
    const int i = blockIdx.x * 256 + threadIdx.x;
    if (i < n4) *(float4*)(p + i * 4) = make_float4(0.f, 0.f, 0.f, 0.f);
}

__global__ __launch_bounds__(256) void proj_kernel(
    const float* __restrict__ x,
    const float* __restrict__ Wq, const float* __restrict__ bq,
    const float* __restrict__ Wk, const float* __restrict__ bk,
    const float* __restrict__ Wv, const float* __restrict__ bv,
    short* __restrict__ Qt, short* __restrict__ Kt, short* __restrict__ Vn)
{
    __shared__ __align__(16) short bufA[64 * LDSK];
    __shared__ __align__(16) short bufB[64 * LDSK];
    const int tid = threadIdx.x;
    const int b  = blockIdx.x >> 6;
    const int n0 = (blockIdx.x & 63) << 6;
    const int wave = tid >> 6, lane = tid & 63;
    const int lo = lane & 15, hi = lane >> 4;

    // Stage x^T (lane = channel -> conflict-free b16 LDS writes)
    {
        const int c = lane;
        for (int p = 0; p < 4; ++p) {
            const float4 v = *(const float4*)(x + ((size_t)(b * C_ + c)) * N_ + n0 + wave * 16 + p * 4);
            bufA[(wave * 16 + p * 4 + 0) * LDSK + c] = f2bf(v.x);
            bufA[(wave * 16 + p * 4 + 1) * LDSK + c] = f2bf(v.y);
            bufA[(wave * 16 + p * 4 + 2) * LDSK + c] = f2bf(v.z);
            bufA[(wave * 16 + p * 4 + 3) * LDSK + c] = f2bf(v.w);
        }
    }
    __syncthreads();

    short8 aX[2];
    aX[0] = *(const short8*)&bufA[(16 * wave + lo) * LDSK + 0 * 32 + hi * 8];
    aX[1] = *(const short8*)&bufA[(16 * wave + lo) * LDSK + 1 * 32 + hi * 8];

    f32x4 qa[4], ka4[4], va[4];
    for (int ot = 0; ot < 4; ++ot) {
        f32x4 acc = {0.f, 0.f, 0.f, 0.f};
        for (int kh = 0; kh < 2; ++kh)
            acc = mfma16(aX[kh], loadWfrag(Wq, ot * 16 + lo, kh * 32 + hi * 8), acc);
        qa[ot] = acc;
    }
    for (int ot = 0; ot < 4; ++ot) {
        f32x4 acc = {0.f, 0.f, 0.f, 0.f};
        for (int kh = 0; kh < 2; ++kh)
            acc = mfma16(aX[kh], loadWfrag(Wk, ot * 16 + lo, kh * 32 + hi * 8), acc);
        ka4[ot] = acc;
    }
    {
        short8 aV[2];
        aV[0] = loadWfrag(Wv, 16 * wave + lo, 0 * 32 + hi * 8);
        aV[1] = loadWfrag(Wv, 16 * wave + lo, 1 * 32 + hi * 8);
        for (int nt = 0; nt < 4; ++nt) {
            f32x4 acc = {0.f, 0.f, 0.f, 0.f};
            for (int kh = 0; kh < 2; ++kh)
                acc = mfma16(aV[kh], *(const short8*)&bufA[(nt * 16 + lo) * LDSK + kh * 32 + hi * 8], acc);
            va[nt] = acc;
        }
    }
    __syncthreads();

    // Repack Q->bufA, K->bufB as [n_local][o]
    for (int ot = 0; ot < 4; ++ot)
        for (int r = 0; r < 4; ++r) {
            const int o = ot * 16 + lo;
            const int row = wave * 16 + hi * 4 + r;
            bufA[row * LDSK + o] = f2bf((qa[ot][r] + bq[o]) * QSCALE);
            bufB[row * LDSK + o] = f2bf(ka4[ot][r] + bk[o]);
        }
    __syncthreads();
    {
        const int row = tid >> 2, ch = tid & 3;
        const size_t gbase = ((size_t)(b * N_ + n0 + row)) * 64;
        *(uint4*)(Qt + gbase + ch * 16)     = *(const uint4*)&bufA[row * LDSK + ch * 16];
        *(uint4*)(Qt + gbase + ch * 16 + 8) = *(const uint4*)&bufA[row * LDSK + ch * 16 + 8];
        *(uint4*)(Kt + gbase + ch * 16)     = *(const uint4*)&bufB[row * LDSK + ch * 16];
        *(uint4*)(Kt + gbase + ch * 16 + 8) = *(const uint4*)&bufB[row * LDSK + ch * 16 + 8];
    }
    __syncthreads();

    // Repack V -> bufA as [c][n_local]
    for (int nt = 0; nt < 4; ++nt)
        for (int r = 0; r < 4; ++r) {
            const int o = wave * 16 + hi * 4 + r;
            bufA[o * LDSK + nt * 16 + lo] = f2bf(va[nt][r] + bv[o]);
        }
    __syncthreads();
    {
        const int row = tid >> 2, ch = tid & 3;
        const size_t gbase = ((size_t)(b * 64 + row)) * N_ + n0;
        *(uint4*)(Vn + gbase + ch * 16)     = *(const uint4*)&bufA[row * LDSK + ch * 16];
        *(uint4*)(Vn + gbase + ch * 16 + 8) = *(const uint4*)&bufA[row * LDSK + ch * 16 + 8];
    }
}

__global__ __launch_bounds__(256, 3) void attn_kernel(
    const short* __restrict__ Qt, const short* __restrict__ Kt, const short* __restrict__ Vn,
    float* __restrict__ pO, float* __restrict__ pL)
{
    __shared__ __align__(16) short kt[BJ * LDSK];   // [j][c]
    __shared__ __align__(16) short vt[64 * LDSV];   // [c][j]

    const int tid = threadIdx.x;
    const int b  = blockIdx.x >> 6;
    const int i0 = (blockIdx.x & 63) << 6;
    const int split = blockIdx.y;
    const int wave = tid >> 6, lane = tid & 63;
    const int lo = lane & 15, hi = lane >> 4;

    // Q B-frags for all 4 i-quarters (global, once)
    short8 qf[4][2];
    for (int iq = 0; iq < 4; ++iq) {
        const size_t qbase = ((size_t)(b * N_ + i0 + iq * 16 + lo)) * 64;
        qf[iq][0] = *(const short8*)(Qt + qbase + 0 * 32 + hi * 8);
        qf[iq][1] = *(const short8*)(Qt + qbase + 1 * 32 + hi * 8);
    }

    f32x4 o_acc[4][4];  // [ct][iq]
    f32x4 l_acc[4];
    for (int ct = 0; ct < 4; ++ct)
        for (int iq = 0; iq < 4; ++iq) o_acc[ct][iq] = (f32x4){0.f, 0.f, 0.f, 0.f};
    for (int iq = 0; iq < 4; ++iq) l_acc[iq] = (f32x4){0.f, 0.f, 0.f, 0.f};

    short8 ones;
    for (int e = 0; e < 8; ++e) ones[e] = (short)0x3F80;  // bf16 1.0

    const int sr_k = tid >> 1, sh_k = tid & 1;  // kt staging: 128 rows x 64 c
    const int sr_v = tid >> 2, sq_v = tid & 3;  // vt staging: 64 rows x 128 j

    for (int rr = 0; rr < (N_ / BJ / SPLIT); ++rr) {
        const int j0 = (split * (N_ / BJ / SPLIT) + rr) * BJ;
        __syncthreads();
        for (int u = 0; u < 4; ++u)
            *(uint4*)&kt[sr_k * LDSK + sh_k * 32 + u * 8] =
                *(const uint4*)(Kt + ((size_t)(b * N_ + j0 + sr_k)) * 64 + sh_k * 32 + u * 8);
        for (int u = 0; u < 4; ++u)
            *(uint4*)&vt[sr_v * LDSV + sq_v * 32 + u * 8] =
                *(const uint4*)(Vn + ((size_t)(b * 64 + sr_v)) * N_ + j0 + sq_v * 32 + u * 8);
        __syncthreads();

        // S^T = K Q^T per 16-j tile of this wave's 32-j window; P = exp2(S^T - M)
        bh4 ph[4][2];  // [iq][jt2]
        for (int jt2 = 0; jt2 < 2; ++jt2) {
            const int jrow = wave * 32 + jt2 * 16;
            const short8 ka0 = *(const short8*)&kt[(jrow + lo) * LDSK + 0 + hi * 8];
            const short8 ka1 = *(const short8*)&kt[(jrow + lo) * LDSK + 32 + hi * 8];
            for (int iq = 0; iq < 4; ++iq) {
                f32x4 st = mfma16(ka0, qf[iq][0], (f32x4){0.f, 0.f, 0.f, 0.f});
                st = mfma16(ka1, qf[iq][1], st);
                bh4 p;
                for (int r = 0; r < 4; ++r)
                    p[r] = f2bf(__builtin_amdgcn_exp2f(st[r] - MSHIFT));
                ph[iq][jt2] = p;
            }
        }
        // Assemble K=32 A-frags (permuted-k: e<4 -> tile0 j=hi*4+e, e>=4 -> tile1)
        short8 pf[4];
        for (int iq = 0; iq < 4; ++iq)
            pf[iq] = __builtin_shufflevector(ph[iq][0], ph[iq][1], 0, 1, 2, 3, 4, 5, 6, 7);

        // O += P V^T (B follows the same permutation: two b64 reads)
        for (int ct = 0; ct < 4; ++ct) {
            const short* vrow = &vt[(ct * 16 + lo) * LDSV + wave * 32 + hi * 4];
            const bh4 va_ = *(const bh4*)vrow;
            const bh4 vb_ = *(const bh4*)(vrow + 16);
            const short8 vf8 = __builtin_shufflevector(va_, vb_, 0, 1, 2, 3, 4, 5, 6, 7);
            for (int iq = 0; iq < 4; ++iq)
                o_acc[ct][iq] = mfma16(pf[iq], vf8, o_acc[ct][iq]);
        }
        // l += P . ones
        for (int iq = 0; iq < 4; ++iq)
            l_acc[iq] = mfma16(pf[iq], ones, l_acc[iq]);
    }

    // Merge partials (rows i = i0 + iq*16 + hi*4 + r, col c = ct*16 + lo)
    for (int ct = 0; ct < 4; ++ct)
        for (int iq = 0; iq < 4; ++iq)
            for (int r = 0; r < 4; ++r)
                atomicAdd(pO + ((size_t)(b * N_ + i0 + iq * 16 + hi * 4 + r)) * 64 + ct * 16 + lo,
                          o_acc[ct][iq][r]);
    if (lo == 0)
        for (int iq = 0; iq < 4; ++iq)
            for (int r = 0; r < 4; ++r)
                atomicAdd(pL + b * N_ + i0 + iq * 16 + hi * 4 + r, l_acc[iq][r]);
}

__global__ __launch_bounds__(256) void combine_kernel(
    const float* __restrict__ pO, const float* __restrict__ pL,
    const float* __restrict__ x, const float* __restrict__ gamma_p,
    float* __restrict__ out)
{
    const int tid = threadIdx.x;
    const int b  = blockIdx.x >> 6;
    const int i0 = (blockIdx.x & 63) << 6;
    const int i_l = tid & 63, cq = tid >> 6;
    const int g = b * N_ + i0 + i_l;
    const float s = gamma_p[0] / pL[g];
    for (int cc = 0; cc < 4; ++cc) {
        const float4 o4 = *(const float4*)(pO + (size_t)g * 64 + cq * 16 + cc * 4);
        const float ov[4] = {o4.x, o4.y, o4.z, o4.w};
        for (int k = 0; k < 4; ++k) {
            const int c = cq * 16 + cc * 4 + k;
            const size_t idx = ((size_t)(b * 64 + c)) * N_ + i0 + i_l;
            out[idx] = ov[k] * s + x[idx];
        }
    }
}

extern "C" void kernel_launch(void* const* d_in, const int* in_sizes, int n_in,
                              void* d_out, int out_size, void* d_ws, size_t ws_size,
                              hipStream_t stream) {
    const float* x     = (const float*)d_in[0];
    const float* Wq    = (const float*)d_in[1];
    const float* bq    = (const float*)d_in[2];
    const float* Wk    = (const float*)d_in[3];
    const float* bk    = (const float*)d_in[4];
    const float* Wv    = (const float*)d_in[5];
    const float* bv    = (const float*)d_in[6];
    const float* gamma = (const float*)d_in[7];
    float* out = (float*)d_out;

    // ws: Qt(2MB) Kt(2MB) Vn(2MB) pO(4MB fp32) pL(64KB fp32)
    short* Qt = (short*)d_ws;
    short* Kt = Qt + (size_t)B_ * N_ * C_;
    short* Vn = Kt + (size_t)B_ * N_ * C_;
    float* pO = (float*)(Vn + (size_t)B_ * N_ * C_);
    float* pL = pO + (size_t)B_ * N_ * C_;

    const int nzero4 = (B_ * N_ * C_ + B_ * N_) / 4;  // fp32 float4 count
    zero_ws<<<dim3((nzero4 + 255) / 256), dim3(256), 0, stream>>>(pO, nzero4);
    proj_kernel<<<dim3(B_ * (N_ / 64)), dim3(256), 0, stream>>>(
        x, Wq, bq, Wk, bk, Wv, bv, Qt, Kt, Vn);
    attn_kernel<<<dim3(B_ * (N_ / 64), SPLIT), dim3(256), 0, stream>>>(Qt, Kt, Vn, pO, pL);
    combine_kernel<<<dim3(B_ * (N_ / 64)), dim3(256), 0, stream>>>(pO, pL, x, gamma, out);
}